// Round 5
// baseline (287.468 us; speedup 1.0000x reference)
//
#include <hip/hip_runtime.h>
#include <stdint.h>

// ProposalLayerSoft: 3x3x3 NMS + per-batch top-10 + coord epilogue.
// Input:  d_in[0] = root_cubes f32 [B=32, X=128, Y=128, Z=64]
// Output: d_out   = f32 [B, 10, 5] = (x,y,z, valid-1, score)
// ws: part = B*400 u64 keys (shared by stream+fallback), then cnt[B] u32.
//
// ROUND 5: STREAMING LDS REWRITE. Evidence r0-r4: peaks dur 79-83us
// invariant to VALU work (36->19% busy), serial chain length (11 vs 19
// loads), prefetch, occupancy (29->42%), emission machinery. Only
// invariant left: ~180 MB logical reads in a 16-way-scattered pattern
// (lane yi stride 256B; every vmem instr touches 16 disjoint line
// pairs) = 2.3 TB/s logical = ~9 B/cyc/CU = the per-CU vmem path
// ceiling for that mix. All visible pipes idle because the wall is the
// CU vmem request path. Fix = make the load stream contiguous:
//   - 1 block/CU (grid 8 slabs x B = 256), 8 waves, 133 KB LDS.
//   - plane ring[4] staged via global_load_lds width=16 (linear 1KB per
//     instr), 1-2 planes in flight, counted vmcnt(4) + raw s_barrier
//     (T3/T4: never drain vmcnt in-loop).
//   - source pre-swizzled chunk^=(y&7) so LDS reads are 2-way-free
//     (rule 21: gload_lds dest must stay linear; swizzle the source).
//   - compute: 4 ds_read_b128 + max16 + 1 ballot per thread-plane;
//     27-max only for >THRV voxels (0.1%) straight from resident ring.
//   - no y-halo re-reads (block spans full y): logical 151 MB.
// Threshold exactness (r4): >=10 peaks >THRV per batch => top-10 all
// >THRV => thresholded emission bitwise-exact. cnt[b] counts peaks>T;
// fallback kernel (r4's verified dense path) reruns any batch with
// cnt<10 or overflow sentinel (never fires on bench: E[cnt]~1035+-32).

#define NK 10
#define NSLAB 8          // x-slabs per batch; grid = (NSLAB, B)
#define SPB 512          // stream block: 8 waves
#define WCAP 64          // per-wave cand cap (mean ~16); overflow -> sentinel
#define THRV 0.999f
// fallback kernel (r4 structure)
#define TPB 256
#define TY 10
#define BLOCKS_PER_B (4 * TY)
#define FWCAP 512

typedef unsigned long long u64;

__device__ __forceinline__ u64 bfly_max_u64(u64 v) {
#pragma unroll
  for (int off = 1; off < 64; off <<= 1) {
    u64 o = __shfl_xor(v, off, 64);
    v = (o > v) ? o : v;
  }
  return v;
}

__device__ __forceinline__ void load_lds16(const float* g, void* l) {
  __builtin_amdgcn_global_load_lds(
      (const __attribute__((address_space(1))) void*)g,
      (__attribute__((address_space(3))) void*)l, 16, 0, 0);
}

// 27-neighborhood max from the resident LDS ring (rare path, noinline so
// the 16x-unrolled j-loop doesn't replicate it -> I$ stays small).
// Swizzled layout: value (y,z) lives at chunk y*16 + ((z>>2) ^ (y&7)).
__device__ __noinline__ float max27(const float* Pp, const float* Cp,
                                    const float* Np, int y, int z) {
  float m = -1e30f;
#pragma unroll
  for (int pp = 0; pp < 3; ++pp) {
    const float* pl = (pp == 0) ? Pp : (pp == 1 ? Cp : Np);
#pragma unroll
    for (int dy = -1; dy <= 1; ++dy) {
      int yy = y + dy;
      if ((unsigned)yy > 127u) continue;
      int yb = yy << 4, yx = yy & 7;
#pragma unroll
      for (int dz = -1; dz <= 1; ++dz) {
        int zz = z + dz;
        if ((unsigned)zz > 63u) continue;
        int ch = yb + (((unsigned)zz >> 2) ^ yx);
        m = fmaxf(m, pl[(ch << 2) + (zz & 3)]);
      }
    }
  }
  return m;
}

__global__ __launch_bounds__(SPB, 2) void peaks_stream(
    const float* __restrict__ in, u64* __restrict__ part,
    unsigned* __restrict__ cnt) {
  __shared__ float ring[4][8192];   // 128 KB: 4-plane ring [y][z] swizzled
  __shared__ u64 cand[8][WCAP];     // 4 KB
  __shared__ u64 wtop[8 * NK];
  __shared__ unsigned wcnts[8];

  const int tid = threadIdx.x;
  const int w = tid >> 6, lane = tid & 63;
  const int y = tid >> 2;           // 0..127 (block spans full y)
  const int zq = tid & 3;           // z quarter: z in [16*zq, 16*zq+16)
  const int slab = blockIdx.x;      // 0..7
  const int b = blockIdx.y;
  const int x0 = slab << 4;
  const float* __restrict__ bat = in + ((size_t)b << 20);

  // Stage plane xp (batch-clamped; dup plane is max-safe) into ring slot
  // s. Dest linear (wave-uniform base + lane*16); source pre-swizzled:
  // dest chunk i = y*16+k  <-  global chunk y*16 + (k ^ (y&7)).
  auto stage = [&](int xp, int s) {
    const int cx = min(127, max(0, xp));
    const float* src = bat + ((size_t)cx << 13);
    float* dst = &ring[s][0];
#pragma unroll
    for (int i = 0; i < 4; ++i) {
      int cbase = (w << 8) + (i << 6);  // wave-uniform dest chunk base
      int ci = cbase + lane;            // this lane's dest chunk
      int cy2 = ci >> 4, k = ci & 15;
      int kg = k ^ (cy2 & 7);
      const float* sp = src + (((cy2 << 4) + kg) << 2);
      load_lds16(sp, (void*)(dst + (cbase << 2)));
    }
  };

  stage(x0 - 1, 0);
  stage(x0,     1);
  stage(x0 + 1, 2);
  stage(x0 + 2, 3);

  int wcnt = 0;  // wave-uniform emitted-peak count (scalar)
  const int ybase = y << 4, yxr = y & 7;

#pragma unroll 1
  for (int t = 0; t < 16; ++t) {
    // Gate: plane t+1 resident (own 4 loads for t+2 may stay in flight).
    if (t == 15) {
      asm volatile("s_waitcnt vmcnt(0)" ::: "memory");
    } else {
      asm volatile("s_waitcnt vmcnt(4)" ::: "memory");
    }
    __builtin_amdgcn_s_barrier();   // raw barrier: no vmcnt auto-drain
    __builtin_amdgcn_sched_barrier(0);

    const float* Pp = &ring[(t) & 3][0];
    const float* Cp = &ring[(t + 1) & 3][0];
    const float* Np = &ring[(t + 2) & 3][0];

    float vC[16];
#pragma unroll
    for (int m = 0; m < 4; ++m) {
      int ch = ybase + (((zq << 2) + m) ^ yxr);
      const float4 q = *(const float4*)(Cp + (ch << 2));
      vC[(m << 2) + 0] = q.x; vC[(m << 2) + 1] = q.y;
      vC[(m << 2) + 2] = q.z; vC[(m << 2) + 3] = q.w;
    }
    float cmax = fmaxf(
        fmaxf(fmaxf(fmaxf(vC[0], vC[1]), fmaxf(vC[2], vC[3])),
              fmaxf(fmaxf(vC[4], vC[5]), fmaxf(vC[6], vC[7]))),
        fmaxf(fmaxf(fmaxf(vC[8], vC[9]), fmaxf(vC[10], vC[11])),
              fmaxf(fmaxf(vC[12], vC[13]), fmaxf(vC[14], vC[15]))));
    if (__ballot(cmax > THRV)) {    // wave-uniform gate (~64% of planes)
      const int x = x0 + t, zb = zq << 4;
#pragma unroll
      for (int j = 0; j < 16; ++j) {
        const float v = vC[j];
        const bool p1 = (v > THRV);
        bool pred = false;
        if (p1) pred = (v >= max27(Pp, Cp, Np, y, zb + j));
        u64 mask = __ballot(pred);
        if (pred) {
          unsigned g = ((unsigned)x << 13) | ((unsigned)y << 6) |
                       (unsigned)(zb + j);
          u64 key = ((u64)__float_as_uint(v) << 32) | (u64)(unsigned)(~g);
          int ofs = __builtin_amdgcn_mbcnt_hi(
              (unsigned)(mask >> 32),
              __builtin_amdgcn_mbcnt_lo((unsigned)mask, 0));
          int slot = wcnt + ofs;
          if (slot < WCAP) cand[w][slot] = key;
        }
        wcnt += (int)__popcll(mask);
      }
    }
    __builtin_amdgcn_s_barrier();   // all reads of slot t-1 done
    __builtin_amdgcn_sched_barrier(0);
    if (t <= 13) stage(x0 + t + 3, (t) & 3);  // overwrite slot of t-1
  }

  // ---- wave top-10 (1 reg: WCAP == 64) ----
  __builtin_amdgcn_s_waitcnt(0);  // drain own-wave LDS writes
  const int count = min(wcnt, WCAP);
  u64 cc = (lane < count) ? cand[w][lane] : 0;
  u64 mine = 0;
#pragma unroll 1
  for (int r = 0; r < NK; ++r) {
    u64 m = bfly_max_u64(cc);
    if (m != 0 && cc == m) cc = 0;  // unique keys: only owner matches
    if (lane == r) mine = m;
  }
  if (lane < NK) wtop[w * NK + lane] = mine;
  if (lane == 0) wcnts[w] = (unsigned)wcnt;
  __syncthreads();

  // ---- block merge 80 -> 10 (wave 0) ----
  if (w == 0) {
    u64 c0 = wtop[lane];  // lanes 0..63 hold first 64 of 80
    u64 c1 = (lane < 8 * NK - 64) ? wtop[64 + lane] : 0;
    u64 mv = 0;
#pragma unroll 1
    for (int r = 0; r < NK; ++r) {
      u64 best = (c0 > c1) ? c0 : c1;
      u64 m = bfly_max_u64(best);
      if (m != 0) {
        if (c0 == m) c0 = 0;
        else if (c1 == m) c1 = 0;
      }
      if (lane == r) mv = m;
    }
    if (lane < NK)
      part[(size_t)b * 400 + slab * NK + lane] = mv;
    if (lane == 0) {
      unsigned s = wcnts[0] + wcnts[1] + wcnts[2] + wcnts[3] +
                   wcnts[4] + wcnts[5] + wcnts[6] + wcnts[7];
      if (s) atomicAdd(&cnt[b], s);
      // Exactness guard: any wave overflow -> force dense fallback.
      bool ovf = false;
#pragma unroll
      for (int i = 0; i < 8; ++i) ovf |= (wcnts[i] > WCAP);
      if (ovf) atomicOr(&cnt[b], 0x80000000u);
    }
  }
}

// ---------------- dense fallback (r4's verified kernel) ----------------
// Early-exits per block when cnt[b]>=10 and no overflow sentinel (always
// on the bench distribution). Writes the full 400-key/batch region.

__device__ __forceinline__ float dpp_nbr_a(float v) {  // row_shl:1
  return __int_as_float(__builtin_amdgcn_update_dpp(
      0, __float_as_int(v), 0x101, 0xF, 0xF, true));
}
__device__ __forceinline__ float dpp_nbr_b(float v) {  // row_shr:1
  return __int_as_float(__builtin_amdgcn_update_dpp(
      0, __float_as_int(v), 0x111, 0xF, 0xF, true));
}

__global__ __launch_bounds__(TPB, 5) void peaks_fallback(
    const float* __restrict__ in, u64* __restrict__ part,
    const unsigned* __restrict__ cnt) {
  __shared__ u64 cand[4][FWCAP];  // 16 KB
  __shared__ u64 wtop[4 * NK];
  const int b = blockIdx.z;
  {
    unsigned cv = cnt[b];
    if (cv < 0x80000000u && cv >= NK) return;  // stream result exact
  }
  const int tid = threadIdx.x;
  const int w = tid >> 6, lane = tid & 63;
  const int yi = lane & 15, zq = lane >> 4;
  const int ty = blockIdx.x;
  const int seg = blockIdx.y * 2 + (w >> 1);
  const int zh = w & 1;
  const int y0 = ty * 14 - 1;
  const int gy = y0 + yi;
  const int cy = min(127, max(0, gy));
  const int x0 = seg << 4;
  const bool emit_ok = (yi >= 1) && (yi <= 14) && (gy <= 127);
  const int zoff = zh * 32 + (zq << 3);
  const int zlo = max(0, zoff - 1);
  const int zhi = min(63, zoff + 8);
  const bool lo_inf = (zq == 0) && (zh == 0);
  const bool hi_inf = (zq == 3) && (zh == 1);
  const float* __restrict__ py = in + ((size_t)b << 20) + ((size_t)cy << 6);

  int wcnt = 0;
  float vP[8], vC[8], vN[8];
  float loP, hiP, loC, hiC, loN, hiN;

  auto loadv = [&](int x, float* v, float& lo, float& hi) {
    const int cx = min(127, max(0, x));
    const float* p = py + ((size_t)cx << 13);
    float4 a = *(const float4*)(p + zoff);
    float4 bb = *(const float4*)(p + zoff + 4);
    v[0] = a.x;  v[1] = a.y;  v[2] = a.z;  v[3] = a.w;
    v[4] = bb.x; v[5] = bb.y; v[6] = bb.z; v[7] = bb.w;
    lo = p[zlo];
    hi = p[zhi];
  };

  loadv(x0 - 1, vP, loP, hiP);
  loadv(x0,     vC, loC, hiC);
  loadv(x0 + 1, vN, loN, hiN);

#pragma unroll 1
  for (int t = 0; t < 16; ++t) {
    const int x = x0 + t;
    {
      float vlP = __shfl_up(vP[7], 16, 64), vrP = __shfl_down(vP[0], 16, 64);
      float vlC = __shfl_up(vC[7], 16, 64), vrC = __shfl_down(vC[0], 16, 64);
      float vlN = __shfl_up(vN[7], 16, 64), vrN = __shfl_down(vN[0], 16, 64);
      vlP = (zq == 0) ? (lo_inf ? -1e30f : loP) : vlP;
      vrP = (zq == 3) ? (hi_inf ? -1e30f : hiP) : vrP;
      vlC = (zq == 0) ? (lo_inf ? -1e30f : loC) : vlC;
      vrC = (zq == 3) ? (hi_inf ? -1e30f : hiC) : vrC;
      vlN = (zq == 0) ? (lo_inf ? -1e30f : loN) : vlN;
      vrN = (zq == 3) ? (hi_inf ? -1e30f : hiN) : vrN;
#pragma unroll
      for (int j = 0; j < 8; ++j) {
        float aP = (j == 0) ? vlP : vP[j - 1];
        float cP = (j == 7) ? vrP : vP[j + 1];
        float aC = (j == 0) ? vlC : vC[j - 1];
        float cC = (j == 7) ? vrC : vC[j + 1];
        float aN = (j == 0) ? vlN : vN[j - 1];
        float cN = (j == 7) ? vrN : vN[j + 1];
        float v = vC[j];
        float zP = fmaxf(aP, fmaxf(vP[j], cP));
        float zC = fmaxf(aC, fmaxf(v, cC));
        float zN = fmaxf(aN, fmaxf(vN[j], cN));
        float xm = fmaxf(zP, fmaxf(zC, zN));
        float l = dpp_nbr_a(xm);
        float r = dpp_nbr_b(xm);
        float m27 = fmaxf(xm, fmaxf(l, r));
        const bool pred = emit_ok && (v >= m27);
        u64 mask = __ballot(pred);
        if (pred) {
          unsigned g = ((unsigned)x << 13) | ((unsigned)gy << 6) |
                       (unsigned)(zoff + j);
          u64 key = ((u64)__float_as_uint(v) << 32) | (u64)(unsigned)(~g);
          int ofs = __builtin_amdgcn_mbcnt_hi(
              (unsigned)(mask >> 32),
              __builtin_amdgcn_mbcnt_lo((unsigned)mask, 0));
          int slot = wcnt + ofs;
          if (slot < FWCAP) cand[w][slot] = key;
        }
        wcnt += (int)__popcll(mask);
      }
    }
#pragma unroll
    for (int j = 0; j < 8; ++j) {
      vP[j] = vC[j];
      vC[j] = vN[j];
    }
    loP = loC; hiP = hiC; loC = loN; hiC = hiN;
    loadv(x + 2, vN, loN, hiN);
  }

  __builtin_amdgcn_s_waitcnt(0);
  const int count = min(wcnt, FWCAP);
  u64 c[FWCAP / 64];
#pragma unroll
  for (int i = 0; i < FWCAP / 64; ++i) {
    int idx = lane + (i << 6);
    c[i] = (idx < count) ? cand[w][idx] : 0;
  }
  u64 mine = 0;
#pragma unroll 1
  for (int r = 0; r < NK; ++r) {
    u64 best = c[0];
#pragma unroll
    for (int i = 1; i < FWCAP / 64; ++i) best = (c[i] > best) ? c[i] : best;
    u64 m = bfly_max_u64(best);
    if (m != 0 && best == m) {
#pragma unroll
      for (int i = 0; i < FWCAP / 64; ++i)
        if (c[i] == m) c[i] = 0;
    }
    if (lane == r) mine = m;
  }
  if (lane < NK) wtop[w * NK + lane] = mine;
  __syncthreads();

  if (w == 0) {
    u64 c0 = (lane < 4 * NK) ? wtop[lane] : 0;
    u64 mv = 0;
#pragma unroll 1
    for (int r = 0; r < NK; ++r) {
      u64 m = bfly_max_u64(c0);
      if (m != 0 && c0 == m) c0 = 0;
      if (lane == r) mv = m;
    }
    if (lane < NK) {
      const int bi = blockIdx.y * TY + ty;  // 0..39
      part[(size_t)b * 400 + bi * NK + lane] = mv;
    }
  }
}

// One wave per batch. Stream path: 80 keys; fallback path: 400 keys.
__global__ __launch_bounds__(64) void final_select(
    const u64* __restrict__ part, const unsigned* __restrict__ cnt,
    float* __restrict__ out) {
  const int lane = threadIdx.x & 63;
  const int b = blockIdx.x;
  const u64* __restrict__ src = part + (size_t)b * 400;
  unsigned cv = cnt[b];
  const bool dense = !(cv < 0x80000000u && cv >= NK);  // fallback ran
  u64 c[7];
  if (dense) {
#pragma unroll
    for (int i = 0; i < 7; ++i) {
      int idx = lane + (i << 6);
      c[i] = (idx < 400) ? src[idx] : 0;
    }
  } else {
    c[0] = src[lane];
    c[1] = (lane < 8 * NK - 64) ? src[64 + lane] : 0;
#pragma unroll
    for (int i = 2; i < 7; ++i) c[i] = 0;
  }
  u64 mine = 0;
#pragma unroll 1
  for (int r = 0; r < NK; ++r) {
    u64 best = c[0];
#pragma unroll
    for (int i = 1; i < 7; ++i) best = (c[i] > best) ? c[i] : best;
    u64 m = bfly_max_u64(best);
    if (m != 0 && best == m) {
#pragma unroll
      for (int i = 0; i < 7; ++i)
        if (c[i] == m) c[i] = 0;
    }
    if (lane == r) mine = m;
  }
  if (lane < NK) {
    float val = 0.0f;
    unsigned g = 0u;
    if (mine != 0) {
      val = __uint_as_float((unsigned)(mine >> 32));
      g = ~((unsigned)mine);
    }
    float fx = (float)(g >> 13) * (8000.0f / 127.0f) - 4000.0f;
    float fy = (float)((g >> 6) & 127u) * (8000.0f / 127.0f) - 4000.0f;
    float fz = (float)(g & 63u) * (2000.0f / 63.0f) - 700.0f;
    float conf = (val > 0.3f) ? 0.0f : -1.0f;
    float* o = out + ((size_t)b * NK + lane) * 5;
    o[0] = fx; o[1] = fy; o[2] = fz; o[3] = conf; o[4] = val;
  }
}

extern "C" void kernel_launch(void* const* d_in, const int* in_sizes, int n_in,
                              void* d_out, int out_size, void* d_ws, size_t ws_size,
                              hipStream_t stream) {
  const float* in = (const float*)d_in[0];
  float* out = (float*)d_out;
  u64* part = (u64*)d_ws;  // B*400 keys (stream: first 80/batch)
  const int B = in_sizes[0] >> 20;  // 128*128*64 = 2^20 elements per batch
  unsigned* cnt =
      (unsigned*)((char*)d_ws + (size_t)B * 400 * sizeof(u64));

  hipMemsetAsync(cnt, 0, (size_t)B * sizeof(unsigned), stream);
  peaks_stream<<<dim3(NSLAB, (unsigned)B), dim3(SPB), 0, stream>>>(in, part,
                                                                   cnt);
  peaks_fallback<<<dim3(TY, 4, (unsigned)B), dim3(TPB), 0, stream>>>(in, part,
                                                                     cnt);
  final_select<<<dim3((unsigned)B), dim3(64), 0, stream>>>(part, cnt, out);
}

// Round 8
// 210.463 us; speedup vs baseline: 1.3659x; 1.3659x over previous
//
#include <hip/hip_runtime.h>
#include <stdint.h>

// ProposalLayerSoft: 3x3x3 NMS + per-batch top-10 + coord epilogue.
// Input:  d_in[0] = root_cubes f32 [B=32, X=128, Y=128, Z=64]
// Output: d_out   = f32 [B, 10, 5] = (x,y,z, valid-1, score)
// ws: part = B*400 u64 (stream uses first 160/batch), then cnt[B] u32.
//
// ROUND 8 = ROUND 6 RESUBMIT #2 (r6: container start failure; r7: GPU
// acquisition timeout — both infra, no GPU signal. Kernel re-audited
// twice: no hang/fault class, barriers block-uniform, accesses bounded,
// ws usage == r4/r5 which passed).
//
// SEQUENTIAL-COALESCED LANE MAP, INDEPENDENT WAVES.
// Theory H (fits all rounds): r0-r4 lane map (yi stride 256B) made every
// vmem instr a 16-row scatter -> HBM random-granule read efficiency
// ~1.17 TB/s (93MB/79.5us), invariant to all in-register changes. The
// harness fill proves 6.9 TB/s sequential on this chip. r5 fixed
// coalescing but died on 1-block/CU barrier lockstep + flat-load max27
// inside the barrier window (148us). This round: lane=(yy=lane>>4,
// zz=lane&15); float4 loads are 1KB contiguous per wave; block reads
// 16KB sequential per plane. Neighbors all in-register: z = shfl+-1
// (16-lane group spans full z; edges are volume edges -> 0-fill, exact
// for v>=0), y = shfl+-16 + one 512B halo load, x = 3-plane register
// rotation. Separable 27-max (x->z->y collapse) only on THRV-gated
// iters (~40%). No main-loop barriers. Grid 512 = 2 blocks/CU exactly,
// all co-resident (launch_bounds(512,4) -> VGPR cap 64; carried state
// 24 floats + temps ~55). Threshold-exactness + fallback: r4 scheme.
// DO NOT: barrier-lockstep streaming (r5), bound past VGPR-cap fit
// (r1 580MB scratch), 256B-strided lane maps (r0-r4 wall).

#define NK 10
#define SPB 512          // stream block: 8 waves, 64 y-rows
#define WCAP 64          // per-wave cand cap (E~8, sigma~2.8); ovf -> sentinel
#define THRV 0.999f
// fallback kernel (r4 structure, verified r4/r5)
#define TPB 256
#define TY 10
#define FWCAP 512

typedef unsigned long long u64;

__device__ __forceinline__ u64 bfly_max_u64(u64 v) {
#pragma unroll
  for (int off = 1; off < 64; off <<= 1) {
    u64 o = __shfl_xor(v, off, 64);
    v = (o > v) ? o : v;
  }
  return v;
}

__device__ __forceinline__ float4 fmax4(float4 a, float4 b) {
  return make_float4(fmaxf(a.x, b.x), fmaxf(a.y, b.y), fmaxf(a.z, b.z),
                     fmaxf(a.w, b.w));
}
__device__ __forceinline__ float4 shflidx4(float4 v, int src) {
  return make_float4(__shfl(v.x, src, 64), __shfl(v.y, src, 64),
                     __shfl(v.z, src, 64), __shfl(v.w, src, 64));
}
__device__ __forceinline__ float4 shflup4(float4 v) {
  return make_float4(__shfl_up(v.x, 16, 64), __shfl_up(v.y, 16, 64),
                     __shfl_up(v.z, 16, 64), __shfl_up(v.w, 16, 64));
}
__device__ __forceinline__ float4 shfldn4(float4 v) {
  return make_float4(__shfl_down(v.x, 16, 64), __shfl_down(v.y, 16, 64),
                     __shfl_down(v.z, 16, 64), __shfl_down(v.w, 16, 64));
}
// z-collapse: 3-wide max along z within a full-z 16-lane group.
// Edge chunks (zz==0/15) are volume edges: 0.0 fill is exact (v >= 0).
__device__ __forceinline__ float4 zmax3(float4 X, int zz) {
  float am = __shfl_up(X.w, 1, 64);
  float bp = __shfl_down(X.x, 1, 64);
  am = (zz == 0) ? 0.0f : am;
  bp = (zz == 15) ? 0.0f : bp;
  float4 Z;
  Z.x = fmaxf(am, fmaxf(X.x, X.y));
  Z.y = fmaxf(X.x, fmaxf(X.y, X.z));
  Z.z = fmaxf(X.y, fmaxf(X.z, X.w));
  Z.w = fmaxf(X.z, fmaxf(X.w, bp));
  return Z;
}

__global__ __launch_bounds__(SPB, 4) void peaks_seq(
    const float* __restrict__ in, u64* __restrict__ part,
    unsigned* __restrict__ cnt) {
  __shared__ u64 cand[8][WCAP];  // 4 KB
  __shared__ u64 wtop[8 * NK];
  __shared__ unsigned wcnts[8];

  const int tid = threadIdx.x;
  const int w = tid >> 6, lane = tid & 63;
  const int zz = lane & 15;        // z chunk: z = zz*4 .. zz*4+3
  const int yy = lane >> 4;        // row within 4-row quad
  const int slab = blockIdx.x;     // 8 x-slabs of 16 planes
  const int yg = blockIdx.y;       // 2 y-halves
  const int b = blockIdx.z;
  const int x0 = slab << 4;
  const int y0 = yg * 64 + w * 8;  // wave rows y0..y0+7
  const float* __restrict__ bat = in + ((size_t)b << 20);

  const int r0 = y0 + yy;          // body load 0: rows y0..y0+3
  const int r1 = y0 + 4 + yy;      // body load 1: rows y0+4..y0+7
  // halo rows (lanes 0-31: y0-1 x2 groups; 32-63: y0+8 x2). Clamp = dup
  // row, max-safe (edge row already in window).
  const int hr = min(127, max(0, (lane & 32) ? (y0 + 8) : (y0 - 1)));
  const size_t o0 = ((size_t)r0 << 6) + (zz << 2);  // float offsets
  const size_t o1 = ((size_t)r1 << 6) + (zz << 2);
  const size_t oh = ((size_t)hr << 6) + (zz << 2);

  auto planep = [&](int xp) {
    return bat + ((size_t)min(127, max(0, xp)) << 13);  // clamp: dup-safe
  };

  float4 P0, P1, C0, C1;
  {
    const float* p = planep(x0 - 1);
    P0 = *(const float4*)(p + o0);
    P1 = *(const float4*)(p + o1);
  }
  {
    const float* p = planep(x0);
    C0 = *(const float4*)(p + o0);
    C1 = *(const float4*)(p + o1);
  }

  int wcnt = 0;  // wave-uniform emitted count (scalar)
#pragma unroll 1
  for (int t = 0; t < 16; ++t) {
    const int x = x0 + t;
    const float* pN = planep(x + 1);
    float4 N0 = *(const float4*)(pN + o0);
    float4 N1 = *(const float4*)(pN + o1);

    float cmax = fmaxf(
        fmaxf(fmaxf(C0.x, C0.y), fmaxf(C0.z, C0.w)),
        fmaxf(fmaxf(C1.x, C1.y), fmaxf(C1.z, C1.w)));
    if (__ballot(cmax > THRV)) {   // wave-uniform gate (~40% of iters)
      // fresh halo rows for the 3 planes (L2-hot: fetched by sibling waves)
      float4 HP = *(const float4*)(planep(x - 1) + oh);
      float4 HC = *(const float4*)(planep(x) + oh);
      float4 HN = *(const float4*)(pN + oh);
      // separable 27-max: x-collapse -> z-collapse -> y-collapse
      float4 X0 = fmax4(fmax4(P0, C0), N0);
      float4 X1 = fmax4(fmax4(P1, C1), N1);
      float4 XH = fmax4(fmax4(HP, HC), HN);
      float4 Z0 = zmax3(X0, zz);
      float4 Z1 = zmax3(X1, zz);
      float4 ZH = zmax3(XH, zz);
      const bool lo16 = (lane < 16), hi16 = (lane >= 48);
      float4 b0 = lo16 ? shflidx4(ZH, zz) : shflup4(Z0);        // row-1
      float4 a0 = hi16 ? shflidx4(Z1, zz) : shfldn4(Z0);        // row+1
      float4 S0 = fmax4(fmax4(b0, Z0), a0);
      float4 b1 = lo16 ? shflidx4(Z0, 48 + zz) : shflup4(Z1);
      float4 a1 = hi16 ? shflidx4(ZH, 32 + zz) : shfldn4(Z1);
      float4 S1 = fmax4(fmax4(b1, Z1), a1);

      const float vj[8] = {C0.x, C0.y, C0.z, C0.w, C1.x, C1.y, C1.z, C1.w};
      const float sj[8] = {S0.x, S0.y, S0.z, S0.w, S1.x, S1.y, S1.z, S1.w};
#pragma unroll
      for (int j = 0; j < 8; ++j) {
        const float v = vj[j];
        const bool pred = (v > THRV) && (v >= sj[j]);  // exact, self-incl.
        u64 mask = __ballot(pred);
        if (pred) {
          const int row = y0 + ((j >> 2) << 2) + yy;
          unsigned g = ((unsigned)x << 13) | ((unsigned)row << 6) |
                       (unsigned)((zz << 2) + (j & 3));
          u64 key = ((u64)__float_as_uint(v) << 32) | (u64)(unsigned)(~g);
          int ofs = __builtin_amdgcn_mbcnt_hi(
              (unsigned)(mask >> 32),
              __builtin_amdgcn_mbcnt_lo((unsigned)mask, 0));
          int slot = wcnt + ofs;
          if (slot < WCAP) cand[w][slot] = key;
        }
        wcnt += (int)__popcll(mask);
      }
    }
    P0 = C0; P1 = C1; C0 = N0; C1 = N1;  // x-rotation (registers)
  }

  // ---- wave top-10 (WCAP == 64 -> 1 reg), no barriers ----
  __builtin_amdgcn_s_waitcnt(0);  // drain own-wave LDS writes
  const int count = min(wcnt, WCAP);
  u64 cc = (lane < count) ? cand[w][lane] : 0;
  u64 mine = 0;
#pragma unroll 1
  for (int r = 0; r < NK; ++r) {
    u64 m = bfly_max_u64(cc);
    if (m != 0 && cc == m) cc = 0;  // unique keys: only owner matches
    if (lane == r) mine = m;
  }
  if (lane < NK) wtop[w * NK + lane] = mine;
  if (lane == 0) wcnts[w] = (unsigned)wcnt;
  __syncthreads();

  // ---- block merge 80 -> 10 (wave 0) ----
  if (w == 0) {
    u64 c0 = wtop[lane];
    u64 c1 = (lane < 8 * NK - 64) ? wtop[64 + lane] : 0;
    u64 mv = 0;
#pragma unroll 1
    for (int r = 0; r < NK; ++r) {
      u64 best = (c0 > c1) ? c0 : c1;
      u64 m = bfly_max_u64(best);
      if (m != 0) {
        if (c0 == m) c0 = 0;
        else if (c1 == m) c1 = 0;
      }
      if (lane == r) mv = m;
    }
    if (lane < NK)
      part[(size_t)b * 400 + (slab * 2 + yg) * NK + lane] = mv;
    if (lane == 0) {
      unsigned s = wcnts[0] + wcnts[1] + wcnts[2] + wcnts[3] +
                   wcnts[4] + wcnts[5] + wcnts[6] + wcnts[7];
      if (s) atomicAdd(&cnt[b], s);
      bool ovf = false;
#pragma unroll
      for (int i = 0; i < 8; ++i) ovf |= (wcnts[i] > WCAP);
      if (ovf) atomicOr(&cnt[b], 0x80000000u);  // force exact fallback
    }
  }
}

// ---------------- dense fallback (r4's verified kernel) ----------------
__device__ __forceinline__ float dpp_nbr_a(float v) {  // row_shl:1
  return __int_as_float(__builtin_amdgcn_update_dpp(
      0, __float_as_int(v), 0x101, 0xF, 0xF, true));
}
__device__ __forceinline__ float dpp_nbr_b(float v) {  // row_shr:1
  return __int_as_float(__builtin_amdgcn_update_dpp(
      0, __float_as_int(v), 0x111, 0xF, 0xF, true));
}

__global__ __launch_bounds__(TPB, 5) void peaks_fallback(
    const float* __restrict__ in, u64* __restrict__ part,
    const unsigned* __restrict__ cnt) {
  __shared__ u64 cand[4][FWCAP];  // 16 KB
  __shared__ u64 wtop[4 * NK];
  const int b = blockIdx.z;
  {
    unsigned cv = cnt[b];
    if (cv < 0x80000000u && cv >= NK) return;  // stream result exact
  }
  const int tid = threadIdx.x;
  const int w = tid >> 6, lane = tid & 63;
  const int yi = lane & 15, zq = lane >> 4;
  const int ty = blockIdx.x;
  const int seg = blockIdx.y * 2 + (w >> 1);
  const int zh = w & 1;
  const int y0 = ty * 14 - 1;
  const int gy = y0 + yi;
  const int cy = min(127, max(0, gy));
  const int x0 = seg << 4;
  const bool emit_ok = (yi >= 1) && (yi <= 14) && (gy <= 127);
  const int zoff = zh * 32 + (zq << 3);
  const int zlo = max(0, zoff - 1);
  const int zhi = min(63, zoff + 8);
  const bool lo_inf = (zq == 0) && (zh == 0);
  const bool hi_inf = (zq == 3) && (zh == 1);
  const float* __restrict__ py = in + ((size_t)b << 20) + ((size_t)cy << 6);

  int wcnt = 0;
  float vP[8], vC[8], vN[8];
  float loP, hiP, loC, hiC, loN, hiN;

  auto loadv = [&](int x, float* v, float& lo, float& hi) {
    const int cx = min(127, max(0, x));
    const float* p = py + ((size_t)cx << 13);
    float4 a = *(const float4*)(p + zoff);
    float4 bb = *(const float4*)(p + zoff + 4);
    v[0] = a.x;  v[1] = a.y;  v[2] = a.z;  v[3] = a.w;
    v[4] = bb.x; v[5] = bb.y; v[6] = bb.z; v[7] = bb.w;
    lo = p[zlo];
    hi = p[zhi];
  };

  loadv(x0 - 1, vP, loP, hiP);
  loadv(x0,     vC, loC, hiC);
  loadv(x0 + 1, vN, loN, hiN);

#pragma unroll 1
  for (int t = 0; t < 16; ++t) {
    const int x = x0 + t;
    {
      float vlP = __shfl_up(vP[7], 16, 64), vrP = __shfl_down(vP[0], 16, 64);
      float vlC = __shfl_up(vC[7], 16, 64), vrC = __shfl_down(vC[0], 16, 64);
      float vlN = __shfl_up(vN[7], 16, 64), vrN = __shfl_down(vN[0], 16, 64);
      vlP = (zq == 0) ? (lo_inf ? -1e30f : loP) : vlP;
      vrP = (zq == 3) ? (hi_inf ? -1e30f : hiP) : vrP;
      vlC = (zq == 0) ? (lo_inf ? -1e30f : loC) : vlC;
      vrC = (zq == 3) ? (hi_inf ? -1e30f : hiC) : vrC;
      vlN = (zq == 0) ? (lo_inf ? -1e30f : loN) : vlN;
      vrN = (zq == 3) ? (hi_inf ? -1e30f : hiN) : vrN;
#pragma unroll
      for (int j = 0; j < 8; ++j) {
        float aP = (j == 0) ? vlP : vP[j - 1];
        float cP = (j == 7) ? vrP : vP[j + 1];
        float aC = (j == 0) ? vlC : vC[j - 1];
        float cC = (j == 7) ? vrC : vC[j + 1];
        float aN = (j == 0) ? vlN : vN[j - 1];
        float cN = (j == 7) ? vrN : vN[j + 1];
        float v = vC[j];
        float zP = fmaxf(aP, fmaxf(vP[j], cP));
        float zC = fmaxf(aC, fmaxf(v, cC));
        float zN = fmaxf(aN, fmaxf(vN[j], cN));
        float xm = fmaxf(zP, fmaxf(zC, zN));
        float l = dpp_nbr_a(xm);
        float r = dpp_nbr_b(xm);
        float m27 = fmaxf(xm, fmaxf(l, r));
        const bool pred = emit_ok && (v >= m27);
        u64 mask = __ballot(pred);
        if (pred) {
          unsigned g = ((unsigned)x << 13) | ((unsigned)gy << 6) |
                       (unsigned)(zoff + j);
          u64 key = ((u64)__float_as_uint(v) << 32) | (u64)(unsigned)(~g);
          int ofs = __builtin_amdgcn_mbcnt_hi(
              (unsigned)(mask >> 32),
              __builtin_amdgcn_mbcnt_lo((unsigned)mask, 0));
          int slot = wcnt + ofs;
          if (slot < FWCAP) cand[w][slot] = key;
        }
        wcnt += (int)__popcll(mask);
      }
    }
#pragma unroll
    for (int j = 0; j < 8; ++j) {
      vP[j] = vC[j];
      vC[j] = vN[j];
    }
    loP = loC; hiP = hiC; loC = loN; hiC = hiN;
    loadv(x + 2, vN, loN, hiN);
  }

  __builtin_amdgcn_s_waitcnt(0);
  const int count = min(wcnt, FWCAP);
  u64 c[FWCAP / 64];
#pragma unroll
  for (int i = 0; i < FWCAP / 64; ++i) {
    int idx = lane + (i << 6);
    c[i] = (idx < count) ? cand[w][idx] : 0;
  }
  u64 mine = 0;
#pragma unroll 1
  for (int r = 0; r < NK; ++r) {
    u64 best = c[0];
#pragma unroll
    for (int i = 1; i < FWCAP / 64; ++i) best = (c[i] > best) ? c[i] : best;
    u64 m = bfly_max_u64(best);
    if (m != 0 && best == m) {
#pragma unroll
      for (int i = 0; i < FWCAP / 64; ++i)
        if (c[i] == m) c[i] = 0;
    }
    if (lane == r) mine = m;
  }
  if (lane < NK) wtop[w * NK + lane] = mine;
  __syncthreads();

  if (w == 0) {
    u64 c0 = (lane < 4 * NK) ? wtop[lane] : 0;
    u64 mv = 0;
#pragma unroll 1
    for (int r = 0; r < NK; ++r) {
      u64 m = bfly_max_u64(c0);
      if (m != 0 && c0 == m) c0 = 0;
      if (lane == r) mv = m;
    }
    if (lane < NK) {
      const int bi = blockIdx.y * TY + ty;  // 0..39
      part[(size_t)b * 400 + bi * NK + lane] = mv;
    }
  }
}

// One wave per batch. Stream path: 160 keys; fallback path: 400 keys.
__global__ __launch_bounds__(64) void final_select(
    const u64* __restrict__ part, const unsigned* __restrict__ cnt,
    float* __restrict__ out) {
  const int lane = threadIdx.x & 63;
  const int b = blockIdx.x;
  const u64* __restrict__ src = part + (size_t)b * 400;
  unsigned cv = cnt[b];
  const bool dense = !(cv < 0x80000000u && cv >= NK);  // fallback ran
  u64 c[7];
  if (dense) {
#pragma unroll
    for (int i = 0; i < 7; ++i) {
      int idx = lane + (i << 6);
      c[i] = (idx < 400) ? src[idx] : 0;
    }
  } else {
    c[0] = src[lane];
    c[1] = src[64 + lane];
    c[2] = (lane < 32) ? src[128 + lane] : 0;
#pragma unroll
    for (int i = 3; i < 7; ++i) c[i] = 0;
  }
  u64 mine = 0;
#pragma unroll 1
  for (int r = 0; r < NK; ++r) {
    u64 best = c[0];
#pragma unroll
    for (int i = 1; i < 7; ++i) best = (c[i] > best) ? c[i] : best;
    u64 m = bfly_max_u64(best);
    if (m != 0 && best == m) {
#pragma unroll
      for (int i = 0; i < 7; ++i)
        if (c[i] == m) c[i] = 0;
    }
    if (lane == r) mine = m;
  }
  if (lane < NK) {
    float val = 0.0f;
    unsigned g = 0u;
    if (mine != 0) {
      val = __uint_as_float((unsigned)(mine >> 32));
      g = ~((unsigned)mine);
    }
    float fx = (float)(g >> 13) * (8000.0f / 127.0f) - 4000.0f;
    float fy = (float)((g >> 6) & 127u) * (8000.0f / 127.0f) - 4000.0f;
    float fz = (float)(g & 63u) * (2000.0f / 63.0f) - 700.0f;
    float conf = (val > 0.3f) ? 0.0f : -1.0f;
    float* o = out + ((size_t)b * NK + lane) * 5;
    o[0] = fx; o[1] = fy; o[2] = fz; o[3] = conf; o[4] = val;
  }
}

extern "C" void kernel_launch(void* const* d_in, const int* in_sizes, int n_in,
                              void* d_out, int out_size, void* d_ws, size_t ws_size,
                              hipStream_t stream) {
  const float* in = (const float*)d_in[0];
  float* out = (float*)d_out;
  u64* part = (u64*)d_ws;  // B*400 keys (stream: first 160/batch)
  const int B = in_sizes[0] >> 20;  // 128*128*64 = 2^20 elements per batch
  unsigned* cnt =
      (unsigned*)((char*)d_ws + (size_t)B * 400 * sizeof(u64));

  hipMemsetAsync(cnt, 0, (size_t)B * sizeof(unsigned), stream);
  peaks_seq<<<dim3(8, 2, (unsigned)B), dim3(SPB), 0, stream>>>(in, part, cnt);
  peaks_fallback<<<dim3(TY, 4, (unsigned)B), dim3(TPB), 0, stream>>>(in, part,
                                                                     cnt);
  final_select<<<dim3((unsigned)B), dim3(64), 0, stream>>>(part, cnt, out);
}